// Round 16
// baseline (157.665 us; speedup 1.0000x reference)
//
#include <hip/hip_runtime.h>
#include <hip/hip_bf16.h>

typedef __bf16 bf16x8 __attribute__((ext_vector_type(8)));
typedef float f32x4 __attribute__((ext_vector_type(4)));
typedef float f32x16 __attribute__((ext_vector_type(16)));
typedef int int4v __attribute__((ext_vector_type(4)));
typedef unsigned int uint4v __attribute__((ext_vector_type(4)));
typedef unsigned short u16x8 __attribute__((ext_vector_type(8)));

#define N_NODES 8192
#define D_FEAT 128

// Round-16: r15 deep-pipeline kernel, compile fix only. r15's BALLOT_ONE
// declared locals b0..b3 which captured the pipeline registers b0..b15
// passed as macro args (shadowing in own initializer -> subscript on
// scalar). Locals renamed wb0..wb3/wbsel/wdv. Semantics unchanged.
// Theory under test (r15): phase 1 held only 4 loads in flight/wave;
// 16-deep double-bank register pipeline -> 128-256 KiB/CU in flight.

// ---------------------------------------------------------------------------
__device__ __forceinline__ bf16x8 unpack_byte(unsigned dword, int sh) {
  unsigned P = ((dword >> sh) & 0xFFu) * 0x8001u;
  uint4v c;
  c[0] = (P & 0x10001u) * 0x3F80u;
  c[1] = ((P >> 2) & 0x10001u) * 0x3F80u;
  c[2] = ((P >> 4) & 0x10001u) * 0x3F80u;
  c[3] = ((P >> 6) & 0x10001u) * 0x3F80u;
  return __builtin_bit_cast(bf16x8, c);
}

// ---------------------------------------------------------------------------
// Bpk fragment build (verified rounds 2-6). Fragment f = kk*256 + ng*64 + l
// holds, at element e: F[sigma(kk*16 + (l>>5)*8 + e)][ng*32 + (l&31)],
// sigma(p) = 256*(p>>8) + 32*((p>>3)&7) + 4*(p&7) + ((p>>6)&3)
__device__ __forceinline__ void bpk32_store(const float* __restrict__ src,
                                            unsigned short* __restrict__ Bpk,
                                            int W) {
  const int kk = W >> 8;
  const int ng = (W >> 6) & 3;
  const int l = W & 63;
  const int d = ng * 32 + (l & 31);
  const int p0 = kk * 16 + (l >> 5) * 8;
  const int n0 = (p0 >> 8) * 256 + ((p0 >> 3) & 7) * 32 + ((p0 >> 6) & 3);
  u16x8 pk;
#pragma unroll
  for (int e = 0; e < 8; ++e) {
    __bf16 v = (__bf16)src[(long)(n0 + 4 * e) * D_FEAT + d];
    pk[e] = __builtin_bit_cast(unsigned short, v);
  }
  *(u16x8*)(Bpk + (long)W * 8) = pk;
}

__global__ __launch_bounds__(256) void bpk_build32_kernel(
    const float* __restrict__ src, unsigned short* __restrict__ Bpk) {
  bpk32_store(src, Bpk, blockIdx.x * 256 + threadIdx.x);
}

// ---------------------------------------------------------------------------
// Two-phase fused layer. Block = rows [32bx, +32), grid 256, 512 thr.
__global__ __launch_bounds__(512, 2) void fused_layer_kernel(
    const int* __restrict__ adj, const unsigned short* __restrict__ Bpk,
    const float* __restrict__ fin, float* __restrict__ fout) {
  __shared__ unsigned bitsF[32][320];             // 40 KiB [chunk][row*10+slot]
  __shared__ int degL[32];
  __shared__ __align__(16) f32x4 red[4][4][64];   // 16 KiB split-K combine

  const int tid = threadIdx.x;
  const int lane = tid & 63;
  const int w = tid >> 6;       // 0..7
  const int ng = w & 3;         // 32-col group (phase 2)
  const int kh2 = w >> 2;       // K-half of each chunk (phase 2)
  const int l31 = lane & 31;
  const int lh = lane >> 5;
  const int lh8 = lh * 8;
  const int m0 = blockIdx.x * 32;
  const int e_ = lane >> 1;     // ballot slot select (r6 semantics)

  if (tid < 32) degL[tid] = 0;
  __syncthreads();

  // ===== Phase 1: sequential panel read, 16-deep double-bank pipeline =====
  // Iteration i covers ints [panel + i*2048, +2048); wave w holds chunk
  // c=(i&3)*8+w, lane l ints 4l..4l+3 (verified r6/r14 ballot mapping).
  const int4v* ap = (const int4v*)(adj + ((long)m0 << 13)) + tid;

  // Macro locals use wb*/wbsel/wdv -- MUST NOT collide with the a0../b0..
  // pipeline register names passed as args (r15 compile failure).
#define BALLOT_ONE(V, I, PC)                                                 \
  {                                                                          \
    unsigned long long wb0 = __ballot((V)[0] != 0);                          \
    unsigned long long wb1 = __ballot((V)[1] != 0);                          \
    unsigned long long wb2 = __ballot((V)[2] != 0);                          \
    unsigned long long wb3 = __ballot((V)[3] != 0);                          \
    PC += __popcll(wb0) + __popcll(wb1) + __popcll(wb2) + __popcll(wb3);     \
    unsigned long long wbsel = wb0;                                          \
    if (e_ == 1) wbsel = wb1;                                                \
    if (e_ == 2) wbsel = wb2;                                                \
    if (e_ == 3) wbsel = wb3;                                                \
    unsigned wdv = (lane & 1) ? (unsigned)(wbsel >> 32) : (unsigned)wbsel;   \
    if (lane < 8)                                                            \
      bitsF[((((I)) & 3) << 3) + w][(((I)) >> 2) * 10 + lane] = wdv;         \
  }

  // Load one 16-iteration group (16 x 8 KiB block-wide) into a bank.
#define LOAD_G(R0, R1, R2, R3, R4, R5, R6, R7, R8, R9, R10, R11, R12, R13,   \
               R14, R15, G)                                                  \
  {                                                                          \
    R0 = ap[((G)*16 + 0) * 512];                                             \
    R1 = ap[((G)*16 + 1) * 512];                                             \
    R2 = ap[((G)*16 + 2) * 512];                                             \
    R3 = ap[((G)*16 + 3) * 512];                                             \
    R4 = ap[((G)*16 + 4) * 512];                                             \
    R5 = ap[((G)*16 + 5) * 512];                                             \
    R6 = ap[((G)*16 + 6) * 512];                                             \
    R7 = ap[((G)*16 + 7) * 512];                                             \
    R8 = ap[((G)*16 + 8) * 512];                                             \
    R9 = ap[((G)*16 + 9) * 512];                                             \
    R10 = ap[((G)*16 + 10) * 512];                                           \
    R11 = ap[((G)*16 + 11) * 512];                                           \
    R12 = ap[((G)*16 + 12) * 512];                                           \
    R13 = ap[((G)*16 + 13) * 512];                                           \
    R14 = ap[((G)*16 + 14) * 512];                                           \
    R15 = ap[((G)*16 + 15) * 512];                                           \
  }

  // Ballot a 4-iteration row-group (one row), then one atomicAdd for deg.
#define BALLOT_4(Ra, Rb, Rc, Rd, IBASE)                                      \
  {                                                                          \
    int wpc = 0;                                                             \
    BALLOT_ONE(Ra, (IBASE) + 0, wpc)                                         \
    BALLOT_ONE(Rb, (IBASE) + 1, wpc)                                         \
    BALLOT_ONE(Rc, (IBASE) + 2, wpc)                                         \
    BALLOT_ONE(Rd, (IBASE) + 3, wpc)                                         \
    if (lane == 0) atomicAdd(&degL[(IBASE) >> 2], wpc);                      \
  }

#define BALLOT_G(R0, R1, R2, R3, R4, R5, R6, R7, R8, R9, R10, R11, R12, R13, \
                 R14, R15, G)                                                \
  {                                                                          \
    BALLOT_4(R0, R1, R2, R3, (G)*16 + 0)                                     \
    BALLOT_4(R4, R5, R6, R7, (G)*16 + 4)                                     \
    BALLOT_4(R8, R9, R10, R11, (G)*16 + 8)                                   \
    BALLOT_4(R12, R13, R14, R15, (G)*16 + 12)                                \
  }

  {
    int4v a0, a1, a2, a3, a4, a5, a6, a7, a8, a9, a10, a11, a12, a13, a14,
        a15;
    int4v b0, b1, b2, b3, b4, b5, b6, b7, b8, b9, b10, b11, b12, b13, b14,
        b15;
    LOAD_G(a0, a1, a2, a3, a4, a5, a6, a7, a8, a9, a10, a11, a12, a13, a14,
           a15, 0)
    for (int g = 0; g < 8; g += 2) {
      if (g + 1 < 8)
        LOAD_G(b0, b1, b2, b3, b4, b5, b6, b7, b8, b9, b10, b11, b12, b13,
               b14, b15, g + 1)
      BALLOT_G(a0, a1, a2, a3, a4, a5, a6, a7, a8, a9, a10, a11, a12, a13,
               a14, a15, g)
      if (g + 2 < 8)
        LOAD_G(a0, a1, a2, a3, a4, a5, a6, a7, a8, a9, a10, a11, a12, a13,
               a14, a15, g + 2)
      BALLOT_G(b0, b1, b2, b3, b4, b5, b6, b7, b8, b9, b10, b11, b12, b13,
               b14, b15, g + 1)
    }
  }
#undef BALLOT_G
#undef BALLOT_4
#undef LOAD_G
#undef BALLOT_ONE
  __syncthreads();

  // ===== Phase 2: GEMM all 32 chunks from LDS bits (r14 verified) =====
  f32x16 acc = {0.f, 0.f, 0.f, 0.f, 0.f, 0.f, 0.f, 0.f,
                0.f, 0.f, 0.f, 0.f, 0.f, 0.f, 0.f, 0.f};

  // B fragment j of chunk c at bpb[c*4096 + j*256] (kk = c*16+kh2*8+j, r6).
  const bf16x8* bpb =
      (const bf16x8*)Bpk + ((kh2 * 8) << 8) + ng * 64 + lane;

#define LOADB(BUF, C)                                                        \
  {                                                                          \
    _Pragma("unroll") for (int j = 0; j < 8; ++j)                            \
        BUF[j] = bpb[(long)(C)*4096 + j * 256];                              \
  }

#define COMPUTE(C, BUF)                                                      \
  {                                                                          \
    const unsigned* bl = &bitsF[(C)][l31 * 10 + kh2 * 4];                    \
    unsigned q0 = bl[0], q1 = bl[1], q2 = bl[2], q3 = bl[3];                 \
    acc = __builtin_amdgcn_mfma_f32_32x32x16_bf16(unpack_byte(q0, lh8),      \
                                                  BUF[0], acc, 0, 0, 0);     \
    acc = __builtin_amdgcn_mfma_f32_32x32x16_bf16(unpack_byte(q0, lh8 + 16), \
                                                  BUF[1], acc, 0, 0, 0);     \
    acc = __builtin_amdgcn_mfma_f32_32x32x16_bf16(unpack_byte(q1, lh8),      \
                                                  BUF[2], acc, 0, 0, 0);     \
    acc = __builtin_amdgcn_mfma_f32_32x32x16_bf16(unpack_byte(q1, lh8 + 16), \
                                                  BUF[3], acc, 0, 0, 0);     \
    acc = __builtin_amdgcn_mfma_f32_32x32x16_bf16(unpack_byte(q2, lh8),      \
                                                  BUF[4], acc, 0, 0, 0);     \
    acc = __builtin_amdgcn_mfma_f32_32x32x16_bf16(unpack_byte(q2, lh8 + 16), \
                                                  BUF[5], acc, 0, 0, 0);     \
    acc = __builtin_amdgcn_mfma_f32_32x32x16_bf16(unpack_byte(q3, lh8),      \
                                                  BUF[6], acc, 0, 0, 0);     \
    acc = __builtin_amdgcn_mfma_f32_32x32x16_bf16(unpack_byte(q3, lh8 + 16), \
                                                  BUF[7], acc, 0, 0, 0);     \
  }

  {
    bf16x8 bbA[8], bbB[8];
    LOADB(bbA, 0)
    for (int c = 0; c < 32; c += 2) {
      LOADB(bbB, c + 1)
      COMPUTE(c, bbA)
      if (c + 2 < 32) LOADB(bbA, c + 2)
      COMPUTE(c + 1, bbB)
    }
  }
#undef COMPUTE
#undef LOADB

  // Split-K2 combine: kh2=1 waves store, kh2=0 waves add (r6 verified).
  if (kh2) {
#define ST4(c)                                                               \
  red[ng][c][lane] = __builtin_shufflevector(acc, acc, 4 * (c), 4 * (c) + 1, \
                                             4 * (c) + 2, 4 * (c) + 3);
    ST4(0) ST4(1) ST4(2) ST4(3)
#undef ST4
  }
  __syncthreads();
  if (kh2) return;
#pragma unroll
  for (int c = 0; c < 4; ++c) {
    f32x4 r = red[ng][c][lane];
#pragma unroll
    for (int k = 0; k < 4; ++k) acc[4 * c + k] += r[k];
  }

  // Epilogue (verified m101 C/D layout): col = ng*32+l31,
  // row32 = (r&3) + 8*(r>>2) + 4*lh.
#pragma unroll
  for (int r = 0; r < 16; ++r) {
    const int row32 = (r & 3) + 8 * (r >> 2) + 4 * lh;
    const int row = m0 + row32;
    const int dg = degL[row32];
    const long off = (long)row * D_FEAT + ng * 32 + l31;
    fout[off] = dg > 0 ? acc[r] * (1.0f / (float)dg) : fin[off];
  }
}

// ---------------------------------------------------------------------------
// Fallback path (round-1 verified), used only if ws too small.
__global__ __launch_bounds__(256) void transpose_cast_kernel(
    const float* __restrict__ src, unsigned short* __restrict__ dst) {
  __shared__ float tile[64][129];
  const int t = threadIdx.x;
  const int nbase = blockIdx.x * 64;
#pragma unroll
  for (int i = 0; i < 32; ++i) {
    int idx = t + i * 256;
    int nl = idx >> 7;
    int d = idx & 127;
    tile[nl][d] = src[(long)(nbase + nl) * D_FEAT + d];
  }
  __syncthreads();
#pragma unroll
  for (int i = 0; i < 32; ++i) {
    int idx = t + i * 256;
    int d = idx >> 6;
    int nl = idx & 63;
    __bf16 b = (__bf16)tile[nl][d];
    dst[(long)d * N_NODES + nbase + nl] = __builtin_bit_cast(unsigned short, b);
  }
}

__global__ __launch_bounds__(512) void layer_kernel_direct(
    const int* __restrict__ adj, const unsigned short* __restrict__ BT,
    const float* __restrict__ fin, float* __restrict__ fout) {
  const int tid = threadIdx.x;
  const int lane = tid & 63;
  const int w = tid >> 6;
  const int m0 = blockIdx.x * 32 + (w >> 2) * 16;
  const int n0 = (w & 3) * 32;
  const int lr = lane & 15;
  const int kc = lane >> 4;

  const int4v* ap = (const int4v*)(adj + (long)(m0 + lr) * N_NODES + kc * 8);
  const bf16x8* bp0 = (const bf16x8*)(BT + (long)(n0 + lr) * N_NODES + kc * 8);
  const bf16x8* bp1 =
      (const bf16x8*)(BT + (long)(n0 + 16 + lr) * N_NODES + kc * 8);

  f32x4 acc0 = {0.f, 0.f, 0.f, 0.f};
  f32x4 acc1 = {0.f, 0.f, 0.f, 0.f};
  int degv = 0;

#pragma unroll 4
  for (int k = 0; k < N_NODES; k += 32) {
    int4v alo = ap[0];
    int4v ahi = ap[1];
    bf16x8 b0 = bp0[0];
    bf16x8 b1 = bp1[0];
    ap += 8;
    bp0 += 4;
    bp1 += 4;
    unsigned short u[8];
    u[0] = alo[0] ? 0x3F80 : 0;
    u[1] = alo[1] ? 0x3F80 : 0;
    u[2] = alo[2] ? 0x3F80 : 0;
    u[3] = alo[3] ? 0x3F80 : 0;
    u[4] = ahi[0] ? 0x3F80 : 0;
    u[5] = ahi[1] ? 0x3F80 : 0;
    u[6] = ahi[2] ? 0x3F80 : 0;
    u[7] = ahi[3] ? 0x3F80 : 0;
    degv += alo[0] + alo[1] + alo[2] + alo[3] + ahi[0] + ahi[1] + ahi[2] +
            ahi[3];
    bf16x8 a;
    memcpy(&a, u, 16);
    acc0 = __builtin_amdgcn_mfma_f32_16x16x32_bf16(a, b0, acc0, 0, 0, 0);
    acc1 = __builtin_amdgcn_mfma_f32_16x16x32_bf16(a, b1, acc1, 0, 0, 0);
  }

  degv += __shfl_xor(degv, 16);
  degv += __shfl_xor(degv, 32);
  int dgv[4];
#pragma unroll
  for (int j = 0; j < 4; ++j) dgv[j] = __shfl(degv, kc * 4 + j);

#pragma unroll
  for (int t = 0; t < 2; ++t) {
    const f32x4 acc = t ? acc1 : acc0;
    const int col = n0 + t * 16 + lr;
#pragma unroll
    for (int j = 0; j < 4; ++j) {
      const long off = (long)(m0 + kc * 4 + j) * D_FEAT + col;
      fout[off] = dgv[j] > 0 ? acc[j] * (1.0f / (float)dgv[j]) : fin[off];
    }
  }
}

// ---------------------------------------------------------------------------
extern "C" void kernel_launch(void* const* d_in, const int* in_sizes, int n_in,
                              void* d_out, int out_size, void* d_ws,
                              size_t ws_size, hipStream_t stream) {
  const float* features = (const float*)d_in[0];
  const int* adj = (const int*)d_in[1];
  float* out = (float*)d_out;
  const long NN = (long)N_NODES * N_NODES;

  const size_t BPK_BYTES = (size_t)D_FEAT * N_NODES * 2;  // 2 MiB
  const size_t NEED = BPK_BYTES + 256;

  if (ws_size >= NEED) {
    unsigned short* Bpk = (unsigned short*)d_ws;

    // Layer 1
    bpk_build32_kernel<<<512, 256, 0, stream>>>(features, Bpk);
    fused_layer_kernel<<<256, 512, 0, stream>>>(adj, Bpk, features, out);
    // Layer 2
    bpk_build32_kernel<<<512, 256, 0, stream>>>(out, Bpk);
    fused_layer_kernel<<<256, 512, 0, stream>>>(adj + NN, Bpk, out, out);
  } else {
    // Fallback: round-1 verified path (needs only 2 MiB ws)
    unsigned short* BTw = (unsigned short*)d_ws;
    transpose_cast_kernel<<<N_NODES / 64, 256, 0, stream>>>(features, BTw);
    layer_kernel_direct<<<N_NODES / 32, 512, 0, stream>>>(adj, BTw, features,
                                                          out);
    transpose_cast_kernel<<<N_NODES / 64, 256, 0, stream>>>(out, BTw);
    layer_kernel_direct<<<N_NODES / 32, 512, 0, stream>>>(adj + NN, BTw, out,
                                                          out);
  }
}

// Round 17
// 156.515 us; speedup vs baseline: 1.0073x; 1.0073x over previous
//
#include <hip/hip_runtime.h>
#include <hip/hip_bf16.h>

typedef __bf16 bf16x8 __attribute__((ext_vector_type(8)));
typedef float f32x4 __attribute__((ext_vector_type(4)));
typedef float f32x16 __attribute__((ext_vector_type(16)));
typedef int int4v __attribute__((ext_vector_type(4)));
typedef unsigned int uint4v __attribute__((ext_vector_type(4)));
typedef unsigned short u16x8 __attribute__((ext_vector_type(8)));

#define N_NODES 8192
#define D_FEAT 128

// Round-17: r14 two-phase kernel at 1024 threads/block (16 waves/CU, 50%
// occupancy vs r14's 25%). Evidence: cold-read rate tracks streaming
// occupancy (r2 full-occ pack 4.45 TB/s vs r14 8-wave 4.0); r16's deep
// pipeline was VGPR-spill-confounded (128-cap vs 128 regs of banks).
// Phase 1: iter i = K-half (i&1) of row (i>>1); wave w holds chunk
// (i&1)*16+w, lane ints 4l..4l+3 == verified r6 ballot layout. Phase 2:
// waves 0-7 run byte-identical r14 GEMM; waves 8-15 barrier-only.

// ---------------------------------------------------------------------------
__device__ __forceinline__ bf16x8 unpack_byte(unsigned dword, int sh) {
  unsigned P = ((dword >> sh) & 0xFFu) * 0x8001u;
  uint4v c;
  c[0] = (P & 0x10001u) * 0x3F80u;
  c[1] = ((P >> 2) & 0x10001u) * 0x3F80u;
  c[2] = ((P >> 4) & 0x10001u) * 0x3F80u;
  c[3] = ((P >> 6) & 0x10001u) * 0x3F80u;
  return __builtin_bit_cast(bf16x8, c);
}

// ---------------------------------------------------------------------------
// Bpk fragment build (verified rounds 2-6). Fragment f = kk*256 + ng*64 + l
// holds, at element e: F[sigma(kk*16 + (l>>5)*8 + e)][ng*32 + (l&31)],
// sigma(p) = 256*(p>>8) + 32*((p>>3)&7) + 4*(p&7) + ((p>>6)&3)
__device__ __forceinline__ void bpk32_store(const float* __restrict__ src,
                                            unsigned short* __restrict__ Bpk,
                                            int W) {
  const int kk = W >> 8;
  const int ng = (W >> 6) & 3;
  const int l = W & 63;
  const int d = ng * 32 + (l & 31);
  const int p0 = kk * 16 + (l >> 5) * 8;
  const int n0 = (p0 >> 8) * 256 + ((p0 >> 3) & 7) * 32 + ((p0 >> 6) & 3);
  u16x8 pk;
#pragma unroll
  for (int e = 0; e < 8; ++e) {
    __bf16 v = (__bf16)src[(long)(n0 + 4 * e) * D_FEAT + d];
    pk[e] = __builtin_bit_cast(unsigned short, v);
  }
  *(u16x8*)(Bpk + (long)W * 8) = pk;
}

__global__ __launch_bounds__(256) void bpk_build32_kernel(
    const float* __restrict__ src, unsigned short* __restrict__ Bpk) {
  bpk32_store(src, Bpk, blockIdx.x * 256 + threadIdx.x);
}

// ---------------------------------------------------------------------------
// Two-phase fused layer. Block = rows [32bx, +32), grid 256, 1024 thr.
__global__ __launch_bounds__(1024, 4) void fused_layer_kernel(
    const int* __restrict__ adj, const unsigned short* __restrict__ Bpk,
    const float* __restrict__ fin, float* __restrict__ fout) {
  __shared__ unsigned bitsF[32][320];             // 40 KiB [chunk][row*10+slot]
  __shared__ int degL[32];
  __shared__ __align__(16) f32x4 red[4][4][64];   // 16 KiB split-K combine

  const int tid = threadIdx.x;
  const int lane = tid & 63;
  const int w = tid >> 6;       // 0..15
  const int ng = w & 3;         // 32-col group (phase 2, waves 0-7)
  const int kh2 = (w >> 2) & 1; // K-half of each chunk (phase 2, waves 0-7)
  const bool gemmw = (w < 8);
  const int l31 = lane & 31;
  const int lh = lane >> 5;
  const int lh8 = lh * 8;
  const int m0 = blockIdx.x * 32;
  const int e_ = lane >> 1;     // ballot slot select (r6 semantics)

  if (tid < 32) degL[tid] = 0;
  __syncthreads();

  // ===== Phase 1: sequential panel read, 16 streaming waves =====
  // Iteration i covers ints [panel + i*4096, +4096) = K-half (i&1) of
  // row (i>>1). Wave w holds chunk (i&1)*16+w, lane l ints 4l..4l+3
  // (verified r6 ballot layout). 64 iterations, 4-deep rolling pipeline.
  const int4v* ap = (const int4v*)(adj + ((long)m0 << 13)) + tid;

#define BALLOT_ONE(V, I)                                                     \
  {                                                                          \
    unsigned long long wb0 = __ballot((V)[0] != 0);                          \
    unsigned long long wb1 = __ballot((V)[1] != 0);                          \
    unsigned long long wb2 = __ballot((V)[2] != 0);                          \
    unsigned long long wb3 = __ballot((V)[3] != 0);                          \
    int wpc = __popcll(wb0) + __popcll(wb1) + __popcll(wb2) + __popcll(wb3); \
    unsigned long long wbsel = wb0;                                          \
    if (e_ == 1) wbsel = wb1;                                                \
    if (e_ == 2) wbsel = wb2;                                                \
    if (e_ == 3) wbsel = wb3;                                                \
    unsigned wdv = (lane & 1) ? (unsigned)(wbsel >> 32) : (unsigned)wbsel;   \
    if (lane < 8)                                                            \
      bitsF[(((I)&1) << 4) + w][((I) >> 1) * 10 + lane] = wdv;               \
    if (lane == 0) atomicAdd(&degL[(I) >> 1], wpc);                          \
  }

  {
    int4v va = ap[0];
    int4v vb = ap[1024];
    int4v vc = ap[2048];
    int4v vd = ap[3072];
    for (int i = 0; i < 64; i += 4) {
      BALLOT_ONE(va, i)
      if (i + 4 < 64) va = ap[(i + 4) * 1024];
      BALLOT_ONE(vb, i + 1)
      if (i + 5 < 64) vb = ap[(i + 5) * 1024];
      BALLOT_ONE(vc, i + 2)
      if (i + 6 < 64) vc = ap[(i + 6) * 1024];
      BALLOT_ONE(vd, i + 3)
      if (i + 7 < 64) vd = ap[(i + 7) * 1024];
    }
  }
#undef BALLOT_ONE
  __syncthreads();

  // ===== Phase 2: waves 0-7 GEMM all 32 chunks from LDS (r14 verified) ====
  f32x16 acc = {0.f, 0.f, 0.f, 0.f, 0.f, 0.f, 0.f, 0.f,
                0.f, 0.f, 0.f, 0.f, 0.f, 0.f, 0.f, 0.f};

  // B fragment j of chunk c at bpb[c*4096 + j*256] (kk = c*16+kh2*8+j, r6).
  const bf16x8* bpb =
      (const bf16x8*)Bpk + ((kh2 * 8) << 8) + ng * 64 + lane;

#define LOADB(BUF, C)                                                        \
  {                                                                          \
    _Pragma("unroll") for (int j = 0; j < 8; ++j)                            \
        BUF[j] = bpb[(long)(C)*4096 + j * 256];                              \
  }

#define COMPUTE(C, BUF)                                                      \
  {                                                                          \
    const unsigned* bl = &bitsF[(C)][l31 * 10 + kh2 * 4];                    \
    unsigned q0 = bl[0], q1 = bl[1], q2 = bl[2], q3 = bl[3];                 \
    acc = __builtin_amdgcn_mfma_f32_32x32x16_bf16(unpack_byte(q0, lh8),      \
                                                  BUF[0], acc, 0, 0, 0);     \
    acc = __builtin_amdgcn_mfma_f32_32x32x16_bf16(unpack_byte(q0, lh8 + 16), \
                                                  BUF[1], acc, 0, 0, 0);     \
    acc = __builtin_amdgcn_mfma_f32_32x32x16_bf16(unpack_byte(q1, lh8),      \
                                                  BUF[2], acc, 0, 0, 0);     \
    acc = __builtin_amdgcn_mfma_f32_32x32x16_bf16(unpack_byte(q1, lh8 + 16), \
                                                  BUF[3], acc, 0, 0, 0);     \
    acc = __builtin_amdgcn_mfma_f32_32x32x16_bf16(unpack_byte(q2, lh8),      \
                                                  BUF[4], acc, 0, 0, 0);     \
    acc = __builtin_amdgcn_mfma_f32_32x32x16_bf16(unpack_byte(q2, lh8 + 16), \
                                                  BUF[5], acc, 0, 0, 0);     \
    acc = __builtin_amdgcn_mfma_f32_32x32x16_bf16(unpack_byte(q3, lh8),      \
                                                  BUF[6], acc, 0, 0, 0);     \
    acc = __builtin_amdgcn_mfma_f32_32x32x16_bf16(unpack_byte(q3, lh8 + 16), \
                                                  BUF[7], acc, 0, 0, 0);     \
  }

  if (gemmw) {
    bf16x8 bbA[8], bbB[8];
    LOADB(bbA, 0)
    for (int c = 0; c < 32; c += 2) {
      LOADB(bbB, c + 1)
      COMPUTE(c, bbA)
      if (c + 2 < 32) LOADB(bbA, c + 2)
      COMPUTE(c + 1, bbB)
    }
  }
#undef COMPUTE
#undef LOADB

  // Split-K2 combine: kh2=1 (waves 4-7) store, kh2=0 (waves 0-3) add.
  if (gemmw && kh2) {
#define ST4(c)                                                               \
  red[ng][c][lane] = __builtin_shufflevector(acc, acc, 4 * (c), 4 * (c) + 1, \
                                             4 * (c) + 2, 4 * (c) + 3);
    ST4(0) ST4(1) ST4(2) ST4(3)
#undef ST4
  }
  __syncthreads();
  if (!gemmw || kh2) return;
#pragma unroll
  for (int c = 0; c < 4; ++c) {
    f32x4 r = red[ng][c][lane];
#pragma unroll
    for (int k = 0; k < 4; ++k) acc[4 * c + k] += r[k];
  }

  // Epilogue (verified m101 C/D layout): col = ng*32+l31,
  // row32 = (r&3) + 8*(r>>2) + 4*lh.
#pragma unroll
  for (int r = 0; r < 16; ++r) {
    const int row32 = (r & 3) + 8 * (r >> 2) + 4 * lh;
    const int row = m0 + row32;
    const int dg = degL[row32];
    const long off = (long)row * D_FEAT + ng * 32 + l31;
    fout[off] = dg > 0 ? acc[r] * (1.0f / (float)dg) : fin[off];
  }
}

// ---------------------------------------------------------------------------
// Fallback path (round-1 verified), used only if ws too small.
__global__ __launch_bounds__(256) void transpose_cast_kernel(
    const float* __restrict__ src, unsigned short* __restrict__ dst) {
  __shared__ float tile[64][129];
  const int t = threadIdx.x;
  const int nbase = blockIdx.x * 64;
#pragma unroll
  for (int i = 0; i < 32; ++i) {
    int idx = t + i * 256;
    int nl = idx >> 7;
    int d = idx & 127;
    tile[nl][d] = src[(long)(nbase + nl) * D_FEAT + d];
  }
  __syncthreads();
#pragma unroll
  for (int i = 0; i < 32; ++i) {
    int idx = t + i * 256;
    int d = idx >> 6;
    int nl = idx & 63;
    __bf16 b = (__bf16)tile[nl][d];
    dst[(long)d * N_NODES + nbase + nl] = __builtin_bit_cast(unsigned short, b);
  }
}

__global__ __launch_bounds__(512) void layer_kernel_direct(
    const int* __restrict__ adj, const unsigned short* __restrict__ BT,
    const float* __restrict__ fin, float* __restrict__ fout) {
  const int tid = threadIdx.x;
  const int lane = tid & 63;
  const int w = tid >> 6;
  const int m0 = blockIdx.x * 32 + (w >> 2) * 16;
  const int n0 = (w & 3) * 32;
  const int lr = lane & 15;
  const int kc = lane >> 4;

  const int4v* ap = (const int4v*)(adj + (long)(m0 + lr) * N_NODES + kc * 8);
  const bf16x8* bp0 = (const bf16x8*)(BT + (long)(n0 + lr) * N_NODES + kc * 8);
  const bf16x8* bp1 =
      (const bf16x8*)(BT + (long)(n0 + 16 + lr) * N_NODES + kc * 8);

  f32x4 acc0 = {0.f, 0.f, 0.f, 0.f};
  f32x4 acc1 = {0.f, 0.f, 0.f, 0.f};
  int degv = 0;

#pragma unroll 4
  for (int k = 0; k < N_NODES; k += 32) {
    int4v alo = ap[0];
    int4v ahi = ap[1];
    bf16x8 b0 = bp0[0];
    bf16x8 b1 = bp1[0];
    ap += 8;
    bp0 += 4;
    bp1 += 4;
    unsigned short u[8];
    u[0] = alo[0] ? 0x3F80 : 0;
    u[1] = alo[1] ? 0x3F80 : 0;
    u[2] = alo[2] ? 0x3F80 : 0;
    u[3] = alo[3] ? 0x3F80 : 0;
    u[4] = ahi[0] ? 0x3F80 : 0;
    u[5] = ahi[1] ? 0x3F80 : 0;
    u[6] = ahi[2] ? 0x3F80 : 0;
    u[7] = ahi[3] ? 0x3F80 : 0;
    degv += alo[0] + alo[1] + alo[2] + alo[3] + ahi[0] + ahi[1] + ahi[2] +
            ahi[3];
    bf16x8 a;
    memcpy(&a, u, 16);
    acc0 = __builtin_amdgcn_mfma_f32_16x16x32_bf16(a, b0, acc0, 0, 0, 0);
    acc1 = __builtin_amdgcn_mfma_f32_16x16x32_bf16(a, b1, acc1, 0, 0, 0);
  }

  degv += __shfl_xor(degv, 16);
  degv += __shfl_xor(degv, 32);
  int dgv[4];
#pragma unroll
  for (int j = 0; j < 4; ++j) dgv[j] = __shfl(degv, kc * 4 + j);

#pragma unroll
  for (int t = 0; t < 2; ++t) {
    const f32x4 acc = t ? acc1 : acc0;
    const int col = n0 + t * 16 + lr;
#pragma unroll
    for (int j = 0; j < 4; ++j) {
      const long off = (long)(m0 + kc * 4 + j) * D_FEAT + col;
      fout[off] = dgv[j] > 0 ? acc[j] * (1.0f / (float)dgv[j]) : fin[off];
    }
  }
}

// ---------------------------------------------------------------------------
extern "C" void kernel_launch(void* const* d_in, const int* in_sizes, int n_in,
                              void* d_out, int out_size, void* d_ws,
                              size_t ws_size, hipStream_t stream) {
  const float* features = (const float*)d_in[0];
  const int* adj = (const int*)d_in[1];
  float* out = (float*)d_out;
  const long NN = (long)N_NODES * N_NODES;

  const size_t BPK_BYTES = (size_t)D_FEAT * N_NODES * 2;  // 2 MiB
  const size_t NEED = BPK_BYTES + 256;

  if (ws_size >= NEED) {
    unsigned short* Bpk = (unsigned short*)d_ws;

    // Layer 1
    bpk_build32_kernel<<<512, 256, 0, stream>>>(features, Bpk);
    fused_layer_kernel<<<256, 1024, 0, stream>>>(adj, Bpk, features, out);
    // Layer 2
    bpk_build32_kernel<<<512, 256, 0, stream>>>(out, Bpk);
    fused_layer_kernel<<<256, 1024, 0, stream>>>(adj + NN, Bpk, out, out);
  } else {
    // Fallback: round-1 verified path (needs only 2 MiB ws)
    unsigned short* BTw = (unsigned short*)d_ws;
    transpose_cast_kernel<<<N_NODES / 64, 256, 0, stream>>>(features, BTw);
    layer_kernel_direct<<<N_NODES / 32, 512, 0, stream>>>(adj, BTw, features,
                                                          out);
    transpose_cast_kernel<<<N_NODES / 64, 256, 0, stream>>>(out, BTw);
    layer_kernel_direct<<<N_NODES / 32, 512, 0, stream>>>(adj + NN, BTw, out,
                                                          out);
  }
}

// Round 18
// 150.305 us; speedup vs baseline: 1.0490x; 1.0413x over previous
//
#include <hip/hip_runtime.h>
#include <hip/hip_bf16.h>

typedef __bf16 bf16x8 __attribute__((ext_vector_type(8)));
typedef float f32x4 __attribute__((ext_vector_type(4)));
typedef float f32x16 __attribute__((ext_vector_type(16)));
typedef int int4v __attribute__((ext_vector_type(4)));
typedef unsigned int uint4v __attribute__((ext_vector_type(4)));
typedef unsigned short u16x8 __attribute__((ext_vector_type(8)));

#define N_NODES 8192
#define D_FEAT 128

// Round-18: REVERT to the round-14 kernel (session best, 149.4 us).
// r17's occupancy doubling (64 KiB/CU in flight) left cold-read BW
// unchanged -> the ~4.3 TB/s read rate is structural, not MLP-limited.
// This is the final configuration: two-phase fused layer (sequential
// 1-MiB panel read + ballot into full-panel LDS bits, then verified r6
// GEMM vs L2-resident Bpk). sigma/Bpk/C-layout verified rounds 2-14.

// ---------------------------------------------------------------------------
__device__ __forceinline__ bf16x8 unpack_byte(unsigned dword, int sh) {
  unsigned P = ((dword >> sh) & 0xFFu) * 0x8001u;
  uint4v c;
  c[0] = (P & 0x10001u) * 0x3F80u;
  c[1] = ((P >> 2) & 0x10001u) * 0x3F80u;
  c[2] = ((P >> 4) & 0x10001u) * 0x3F80u;
  c[3] = ((P >> 6) & 0x10001u) * 0x3F80u;
  return __builtin_bit_cast(bf16x8, c);
}

// ---------------------------------------------------------------------------
// Bpk fragment build (verified rounds 2-6). Fragment f = kk*256 + ng*64 + l
// holds, at element e: F[sigma(kk*16 + (l>>5)*8 + e)][ng*32 + (l&31)],
// sigma(p) = 256*(p>>8) + 32*((p>>3)&7) + 4*(p&7) + ((p>>6)&3)
__device__ __forceinline__ void bpk32_store(const float* __restrict__ src,
                                            unsigned short* __restrict__ Bpk,
                                            int W) {
  const int kk = W >> 8;
  const int ng = (W >> 6) & 3;
  const int l = W & 63;
  const int d = ng * 32 + (l & 31);
  const int p0 = kk * 16 + (l >> 5) * 8;
  const int n0 = (p0 >> 8) * 256 + ((p0 >> 3) & 7) * 32 + ((p0 >> 6) & 3);
  u16x8 pk;
#pragma unroll
  for (int e = 0; e < 8; ++e) {
    __bf16 v = (__bf16)src[(long)(n0 + 4 * e) * D_FEAT + d];
    pk[e] = __builtin_bit_cast(unsigned short, v);
  }
  *(u16x8*)(Bpk + (long)W * 8) = pk;
}

__global__ __launch_bounds__(256) void bpk_build32_kernel(
    const float* __restrict__ src, unsigned short* __restrict__ Bpk) {
  bpk32_store(src, Bpk, blockIdx.x * 256 + threadIdx.x);
}

// ---------------------------------------------------------------------------
// Two-phase fused layer. Block = rows [32bx, +32), grid 256, 512 thr.
__global__ __launch_bounds__(512, 2) void fused_layer_kernel(
    const int* __restrict__ adj, const unsigned short* __restrict__ Bpk,
    const float* __restrict__ fin, float* __restrict__ fout) {
  __shared__ unsigned bitsF[32][320];             // 40 KiB [chunk][row*10+slot]
  __shared__ int degL[32];
  __shared__ __align__(16) f32x4 red[4][4][64];   // 16 KiB split-K combine

  const int tid = threadIdx.x;
  const int lane = tid & 63;
  const int w = tid >> 6;       // 0..7
  const int ng = w & 3;         // 32-col group (phase 2)
  const int kh2 = w >> 2;       // K-half of each chunk (phase 2)
  const int l31 = lane & 31;
  const int lh = lane >> 5;
  const int lh8 = lh * 8;
  const int m0 = blockIdx.x * 32;
  const int e_ = lane >> 1;     // ballot slot select (r6 semantics)

  if (tid < 32) degL[tid] = 0;
  __syncthreads();

  // ===== Phase 1: sequential panel read + ballot-pack =====
  // Iteration i: threads cover ints [panel + i*2048, +2048) = quarter
  // (i&3) of row (i>>2). Wave w holds chunk c=(i&3)*8+w; lane l ints
  // [c*256+4l, +4) -- identical per-wave layout to verified r6 ballot.
  const int4v* ap = (const int4v*)(adj + ((long)m0 << 13)) + tid;

#define BALLOT_ONE(V, I, PC)                                                 \
  {                                                                          \
    unsigned long long b0 = __ballot((V)[0] != 0);                           \
    unsigned long long b1 = __ballot((V)[1] != 0);                           \
    unsigned long long b2 = __ballot((V)[2] != 0);                           \
    unsigned long long b3 = __ballot((V)[3] != 0);                           \
    PC += __popcll(b0) + __popcll(b1) + __popcll(b2) + __popcll(b3);         \
    unsigned long long bsel = b0;                                            \
    if (e_ == 1) bsel = b1;                                                  \
    if (e_ == 2) bsel = b2;                                                  \
    if (e_ == 3) bsel = b3;                                                  \
    unsigned dv = (lane & 1) ? (unsigned)(bsel >> 32) : (unsigned)bsel;      \
    if (lane < 8)                                                            \
      bitsF[((((I)) & 3) << 3) + w][(((I)) >> 2) * 10 + lane] = dv;          \
  }

  {
    int4v va = ap[0];
    int4v vb = ap[512];
    int4v vc = ap[1024];
    int4v vd = ap[1536];
    for (int i = 0; i < 128; i += 4) {
      int pc = 0;
      BALLOT_ONE(va, i, pc)
      if (i + 4 < 128) va = ap[(i + 4) * 512];
      BALLOT_ONE(vb, i + 1, pc)
      if (i + 5 < 128) vb = ap[(i + 5) * 512];
      BALLOT_ONE(vc, i + 2, pc)
      if (i + 6 < 128) vc = ap[(i + 6) * 512];
      BALLOT_ONE(vd, i + 3, pc)
      if (i + 7 < 128) vd = ap[(i + 7) * 512];
      if (lane == 0) atomicAdd(&degL[i >> 2], pc);  // all 4 iters same row
    }
  }
#undef BALLOT_ONE
  __syncthreads();

  // ===== Phase 2: GEMM all 32 chunks from LDS bits =====
  f32x16 acc = {0.f, 0.f, 0.f, 0.f, 0.f, 0.f, 0.f, 0.f,
                0.f, 0.f, 0.f, 0.f, 0.f, 0.f, 0.f, 0.f};

  // B fragment j of chunk c at bpb[c*4096 + j*256] (kk = c*16+kh2*8+j, r6).
  const bf16x8* bpb =
      (const bf16x8*)Bpk + ((kh2 * 8) << 8) + ng * 64 + lane;

#define LOADB(BUF, C)                                                        \
  {                                                                          \
    _Pragma("unroll") for (int j = 0; j < 8; ++j)                            \
        BUF[j] = bpb[(long)(C)*4096 + j * 256];                              \
  }

#define COMPUTE(C, BUF)                                                      \
  {                                                                          \
    const unsigned* bl = &bitsF[(C)][l31 * 10 + kh2 * 4];                    \
    unsigned q0 = bl[0], q1 = bl[1], q2 = bl[2], q3 = bl[3];                 \
    acc = __builtin_amdgcn_mfma_f32_32x32x16_bf16(unpack_byte(q0, lh8),      \
                                                  BUF[0], acc, 0, 0, 0);     \
    acc = __builtin_amdgcn_mfma_f32_32x32x16_bf16(unpack_byte(q0, lh8 + 16), \
                                                  BUF[1], acc, 0, 0, 0);     \
    acc = __builtin_amdgcn_mfma_f32_32x32x16_bf16(unpack_byte(q1, lh8),      \
                                                  BUF[2], acc, 0, 0, 0);     \
    acc = __builtin_amdgcn_mfma_f32_32x32x16_bf16(unpack_byte(q1, lh8 + 16), \
                                                  BUF[3], acc, 0, 0, 0);     \
    acc = __builtin_amdgcn_mfma_f32_32x32x16_bf16(unpack_byte(q2, lh8),      \
                                                  BUF[4], acc, 0, 0, 0);     \
    acc = __builtin_amdgcn_mfma_f32_32x32x16_bf16(unpack_byte(q2, lh8 + 16), \
                                                  BUF[5], acc, 0, 0, 0);     \
    acc = __builtin_amdgcn_mfma_f32_32x32x16_bf16(unpack_byte(q3, lh8),      \
                                                  BUF[6], acc, 0, 0, 0);     \
    acc = __builtin_amdgcn_mfma_f32_32x32x16_bf16(unpack_byte(q3, lh8 + 16), \
                                                  BUF[7], acc, 0, 0, 0);     \
  }

  {
    bf16x8 bA[8], bB[8];
    LOADB(bA, 0)
    for (int c = 0; c < 32; c += 2) {
      LOADB(bB, c + 1)
      COMPUTE(c, bA)
      if (c + 2 < 32) LOADB(bA, c + 2)
      COMPUTE(c + 1, bB)
    }
  }
#undef COMPUTE
#undef LOADB

  // Split-K2 combine: kh2=1 waves store, kh2=0 waves add (r6 verified).
  if (kh2) {
#define ST4(c)                                                               \
  red[ng][c][lane] = __builtin_shufflevector(acc, acc, 4 * (c), 4 * (c) + 1, \
                                             4 * (c) + 2, 4 * (c) + 3);
    ST4(0) ST4(1) ST4(2) ST4(3)
#undef ST4
  }
  __syncthreads();
  if (kh2) return;
#pragma unroll
  for (int c = 0; c < 4; ++c) {
    f32x4 r = red[ng][c][lane];
#pragma unroll
    for (int k = 0; k < 4; ++k) acc[4 * c + k] += r[k];
  }

  // Epilogue (verified m101 C/D layout): col = ng*32+l31,
  // row32 = (r&3) + 8*(r>>2) + 4*lh.
#pragma unroll
  for (int r = 0; r < 16; ++r) {
    const int row32 = (r & 3) + 8 * (r >> 2) + 4 * lh;
    const int row = m0 + row32;
    const int dg = degL[row32];
    const long off = (long)row * D_FEAT + ng * 32 + l31;
    fout[off] = dg > 0 ? acc[r] * (1.0f / (float)dg) : fin[off];
  }
}

// ---------------------------------------------------------------------------
// Fallback path (round-1 verified), used only if ws too small.
__global__ __launch_bounds__(256) void transpose_cast_kernel(
    const float* __restrict__ src, unsigned short* __restrict__ dst) {
  __shared__ float tile[64][129];
  const int t = threadIdx.x;
  const int nbase = blockIdx.x * 64;
#pragma unroll
  for (int i = 0; i < 32; ++i) {
    int idx = t + i * 256;
    int nl = idx >> 7;
    int d = idx & 127;
    tile[nl][d] = src[(long)(nbase + nl) * D_FEAT + d];
  }
  __syncthreads();
#pragma unroll
  for (int i = 0; i < 32; ++i) {
    int idx = t + i * 256;
    int d = idx >> 6;
    int nl = idx & 63;
    __bf16 b = (__bf16)tile[nl][d];
    dst[(long)d * N_NODES + nbase + nl] = __builtin_bit_cast(unsigned short, b);
  }
}

__global__ __launch_bounds__(512) void layer_kernel_direct(
    const int* __restrict__ adj, const unsigned short* __restrict__ BT,
    const float* __restrict__ fin, float* __restrict__ fout) {
  const int tid = threadIdx.x;
  const int lane = tid & 63;
  const int w = tid >> 6;
  const int m0 = blockIdx.x * 32 + (w >> 2) * 16;
  const int n0 = (w & 3) * 32;
  const int lr = lane & 15;
  const int kc = lane >> 4;

  const int4v* ap = (const int4v*)(adj + (long)(m0 + lr) * N_NODES + kc * 8);
  const bf16x8* bp0 = (const bf16x8*)(BT + (long)(n0 + lr) * N_NODES + kc * 8);
  const bf16x8* bp1 =
      (const bf16x8*)(BT + (long)(n0 + 16 + lr) * N_NODES + kc * 8);

  f32x4 acc0 = {0.f, 0.f, 0.f, 0.f};
  f32x4 acc1 = {0.f, 0.f, 0.f, 0.f};
  int degv = 0;

#pragma unroll 4
  for (int k = 0; k < N_NODES; k += 32) {
    int4v alo = ap[0];
    int4v ahi = ap[1];
    bf16x8 b0 = bp0[0];
    bf16x8 b1 = bp1[0];
    ap += 8;
    bp0 += 4;
    bp1 += 4;
    unsigned short u[8];
    u[0] = alo[0] ? 0x3F80 : 0;
    u[1] = alo[1] ? 0x3F80 : 0;
    u[2] = alo[2] ? 0x3F80 : 0;
    u[3] = alo[3] ? 0x3F80 : 0;
    u[4] = ahi[0] ? 0x3F80 : 0;
    u[5] = ahi[1] ? 0x3F80 : 0;
    u[6] = ahi[2] ? 0x3F80 : 0;
    u[7] = ahi[3] ? 0x3F80 : 0;
    degv += alo[0] + alo[1] + alo[2] + alo[3] + ahi[0] + ahi[1] + ahi[2] +
            ahi[3];
    bf16x8 a;
    memcpy(&a, u, 16);
    acc0 = __builtin_amdgcn_mfma_f32_16x16x32_bf16(a, b0, acc0, 0, 0, 0);
    acc1 = __builtin_amdgcn_mfma_f32_16x16x32_bf16(a, b1, acc1, 0, 0, 0);
  }

  degv += __shfl_xor(degv, 16);
  degv += __shfl_xor(degv, 32);
  int dgv[4];
#pragma unroll
  for (int j = 0; j < 4; ++j) dgv[j] = __shfl(degv, kc * 4 + j);

#pragma unroll
  for (int t = 0; t < 2; ++t) {
    const f32x4 acc = t ? acc1 : acc0;
    const int col = n0 + t * 16 + lr;
#pragma unroll
    for (int j = 0; j < 4; ++j) {
      const long off = (long)(m0 + kc * 4 + j) * D_FEAT + col;
      fout[off] = dgv[j] > 0 ? acc[j] * (1.0f / (float)dgv[j]) : fin[off];
    }
  }
}

// ---------------------------------------------------------------------------
extern "C" void kernel_launch(void* const* d_in, const int* in_sizes, int n_in,
                              void* d_out, int out_size, void* d_ws,
                              size_t ws_size, hipStream_t stream) {
  const float* features = (const float*)d_in[0];
  const int* adj = (const int*)d_in[1];
  float* out = (float*)d_out;
  const long NN = (long)N_NODES * N_NODES;

  const size_t BPK_BYTES = (size_t)D_FEAT * N_NODES * 2;  // 2 MiB
  const size_t NEED = BPK_BYTES + 256;

  if (ws_size >= NEED) {
    unsigned short* Bpk = (unsigned short*)d_ws;

    // Layer 1
    bpk_build32_kernel<<<512, 256, 0, stream>>>(features, Bpk);
    fused_layer_kernel<<<256, 512, 0, stream>>>(adj, Bpk, features, out);
    // Layer 2
    bpk_build32_kernel<<<512, 256, 0, stream>>>(out, Bpk);
    fused_layer_kernel<<<256, 512, 0, stream>>>(adj + NN, Bpk, out, out);
  } else {
    // Fallback: round-1 verified path (needs only 2 MiB ws)
    unsigned short* BTw = (unsigned short*)d_ws;
    transpose_cast_kernel<<<N_NODES / 64, 256, 0, stream>>>(features, BTw);
    layer_kernel_direct<<<N_NODES / 32, 512, 0, stream>>>(adj, BTw, features,
                                                          out);
    transpose_cast_kernel<<<N_NODES / 64, 256, 0, stream>>>(out, BTw);
    layer_kernel_direct<<<N_NODES / 32, 512, 0, stream>>>(adj + NN, BTw, out,
                                                          out);
  }
}